// Round 8
// baseline (66.418 us; speedup 1.0000x reference)
//
#include <hip/hip_runtime.h>

typedef unsigned int u32;
typedef unsigned short u16;
typedef _Float16 f16;
typedef __attribute__((ext_vector_type(2))) _Float16 f16x2;
typedef __attribute__((ext_vector_type(4))) _Float16 f16x4;
typedef __attribute__((ext_vector_type(8))) _Float16 f16x8;
typedef __attribute__((ext_vector_type(4))) float f32x4;

#if __has_builtin(__builtin_amdgcn_mfma_f32_16x16x16f16)
#define USE_K16 1
#else
#define USE_K16 0
#endif

__device__ __forceinline__ float bf16_lo(u32 u) { u32 x = u << 16; return __builtin_bit_cast(float, x); }
__device__ __forceinline__ float bf16_hi(u32 u) { u32 x = u & 0xffff0000u; return __builtin_bit_cast(float, x); }
__device__ __forceinline__ float bf16f(u16 v) { u32 x = ((u32)v) << 16; return __builtin_bit_cast(float, x); }
__device__ __forceinline__ u16 f2bf(float f) {  // round-to-nearest-even (proven)
    u32 x = __builtin_bit_cast(u32, f);
    return (u16)((x + 0x7fffu + ((x >> 16) & 1u)) >> 16);
}

// ---------------------------------------------------------------------------
// k_prep: featp[row][col] = bf16(feat[row][col]) for col<25, else 0. (VERBATIM r7)
// ---------------------------------------------------------------------------
__global__ __launch_bounds__(256) void k_prep(const float* __restrict__ feat,
                                              u16* __restrict__ featp, int N) {
    int t = blockIdx.x * 256 + threadIdx.x;
    int row = t >> 5, col = t & 31;
    if (row >= N) return;
    featp[(size_t)row * 32 + col] = (col < 25) ? f2bf(feat[(size_t)row * 25 + col]) : (u16)0;
}

// ---------------------------------------------------------------------------
// M[row][col]: the folded layer-1 matrix (K rows x 128 out cols).
//  rows seg*28+k (k<25):  col<64:  W[k][col]*softmaxT(col)[seg]/32
//                         col>=64: -W[k][col-64]*softmaxB(col-64)[seg]/32
//  rows 84+k (k<25):      col>=64: W[k][col-64]   (self term), else 0
//  all other rows: 0
// ---------------------------------------------------------------------------
__device__ float m_val(int row, int col, const float* __restrict__ W,
                       const float* __restrict__ a1) {
    if (row >= 84) {
        int k = row - 84;
        return (k < 25 && col >= 64) ? W[k * 64 + (col - 64)] : 0.f;
    }
    int seg = (row >= 56) ? 2 : (row >= 28) ? 1 : 0;
    int k = row - seg * 28;
    if (k >= 25) return 0.f;
    int cc = (col < 64) ? col : col - 64;
    int arow = (col < 64) ? cc : 64 + cc;
    float e0 = __expf(a1[arow * 3 + 0]);
    float e1 = __expf(a1[arow * 3 + 1]);
    float e2 = __expf(a1[arow * 3 + 2]);
    float wt = ((seg == 0) ? e0 : (seg == 1) ? e1 : e2) / (e0 + e1 + e2);
    float v = W[k * 64 + cc] * wt * (1.f / 32.f);
    return (col < 64) ? v : -v;
}

// k_prepM: Bpack = M pre-packed into MFMA B-fragment order. 16384 f16 = 32KB.
//  K16 layout: Bpack[((ct*8+ks)*64+l)*4+j]  = M[ks*16 + (l>>4)*4 + j][ct*16 + (l&15)]
//  K32 layout: Bpack[((ct*4+ks)*64+l)*8+j]  = M[ks*32 + (l>>4)*8 + j][ct*16 + (l&15)]
__global__ __launch_bounds__(256) void k_prepM(const float* __restrict__ W,
                                               const float* __restrict__ a1,
                                               f16* __restrict__ Bpack) {
    int idx = blockIdx.x * 256 + threadIdx.x;   // 64 blocks -> 16384
#if USE_K16
    int j = idx & 3, l = (idx >> 2) & 63, ks = (idx >> 8) & 7, ct = idx >> 11;
    int row = ks * 16 + ((l >> 4) << 2) + j;
#else
    int j = idx & 7, l = (idx >> 3) & 63, ks = (idx >> 9) & 3, ct = idx >> 11;
    int row = ks * 32 + ((l >> 4) << 3) + j;
#endif
    int col = ct * 16 + (l & 15);
    float v = (row < 112) ? m_val(row, col, W, a1) : 0.f;
    Bpack[idx] = (f16)v;
}

// ---------------------------------------------------------------------------
// k_gather: round-7 k_layer1 gather section VERBATIM; writes x-rows instead.
//   xbuf[i][r*28 + k]  = f16( sum_{32 nb} featp[adj[r,i,nb], k] )   k<28 (25+pad0)
//   xbuf[i][84 + k]    = f16( feat[i][k] )                          k<25, pad0 to 111
//   cols 112..127 never written (M rows 112+ are zero -> no effect).
// ---------------------------------------------------------------------------
__global__ __launch_bounds__(256) void k_gather(const float* __restrict__ feat,
                                                const u16* __restrict__ featp,
                                                const int* __restrict__ adj,
                                                f16* __restrict__ xbuf, int N) {
    int wave = threadIdx.x >> 6;
    int lane = threadIdx.x & 63;
    int i = blockIdx.x * 4 + wave;
    if (i >= N) return;
    int g = lane >> 4;    // neighbor subgroup 0..3
    int c = lane & 15;    // column-pair index: cols 2c, 2c+1

    const u32* fp = (const u32*)featp;  // 16 u32 per padded row

#pragma unroll
    for (int r = 0; r < 3; ++r) {
        const int* arow = adj + ((size_t)r * N + i) * 32;
        float s0 = 0.f, s1 = 0.f;
#pragma unroll
        for (int it = 0; it < 8; ++it) {
            int nb = arow[it * 4 + g];          // 16 lanes share addr -> broadcast
            u32 u = fp[nb * 16 + c];            // 64B per group, coalesced
            s0 += bf16_lo(u);
            s1 += bf16_hi(u);
        }
        s0 += __shfl_xor(s0, 16, 64); s0 += __shfl_xor(s0, 32, 64);
        s1 += __shfl_xor(s1, 16, 64); s1 += __shfl_xor(s1, 32, 64);
        if (g == 0 && c < 14) {      // cols r*28 + [2c, 2c+1]; featp pad keeps c>=12 zeros
            f16x2 o;
            o[0] = (f16)s0;
            o[1] = (f16)s1;
            *(u32*)(xbuf + (size_t)i * 128 + r * 28 + 2 * c) = __builtin_bit_cast(u32, o);
        }
    }
    if (lane < 28)   // feat segment cols 84..111 (25 real + 3 pad)
        xbuf[(size_t)i * 128 + 84 + lane] = (lane < 25) ? (f16)feat[(size_t)i * 25 + lane] : (f16)0.f;
}

// ---------------------------------------------------------------------------
// k_mfma: w1[i0+0..15][0..127] = x[16 nodes] @ M via MFMA. One wave / 16 nodes.
//  A frag (16x16x16f16): row=l&15 (node), k=4*(l>>4)+j     [documented CDNA layout]
//  D frag: col=l&15 (out col), row=4*(l>>4)+reg (node)     [m89, shape-determined]
// ---------------------------------------------------------------------------
__global__ __launch_bounds__(256) void k_mfma(const f16* __restrict__ xbuf,
                                              const f16* __restrict__ Bpack,
                                              u16* __restrict__ w1, int N) {
    int unit = blockIdx.x * 4 + (threadIdx.x >> 6);
    if (unit * 16 >= N) return;
    int l = threadIdx.x & 63;
    int i0 = unit * 16;
#if USE_K16
    f16x4 a[8];
    const f16* xrow = xbuf + (size_t)(i0 + (l & 15)) * 128 + ((l >> 4) << 2);
#pragma unroll
    for (int ks = 0; ks < 8; ++ks) a[ks] = *(const f16x4*)(xrow + ks * 16);
#pragma unroll
    for (int ct = 0; ct < 8; ++ct) {
        f32x4 d = {0.f, 0.f, 0.f, 0.f};
        const f16* bp = Bpack + ((size_t)(ct * 8) * 64 + l) * 4;
#pragma unroll
        for (int ks = 0; ks < 8; ++ks) {
            f16x4 b = *(const f16x4*)(bp + ks * 256);
            d = __builtin_amdgcn_mfma_f32_16x16x16f16(a[ks], b, d, 0, 0, 0);
        }
#pragma unroll
        for (int reg = 0; reg < 4; ++reg) {
            int node = i0 + ((l >> 4) << 2) + reg;
            if (node < N) w1[(size_t)node * 128 + ct * 16 + (l & 15)] = f2bf(d[reg]);
        }
    }
#else
    f16x8 a[4];
    const f16* xrow = xbuf + (size_t)(i0 + (l & 15)) * 128 + ((l >> 4) << 3);
#pragma unroll
    for (int ks = 0; ks < 4; ++ks) a[ks] = *(const f16x8*)(xrow + ks * 32);
#pragma unroll
    for (int ct = 0; ct < 8; ++ct) {
        f32x4 d = {0.f, 0.f, 0.f, 0.f};
        const f16* bp = Bpack + ((size_t)(ct * 4) * 64 + l) * 8;
#pragma unroll
        for (int ks = 0; ks < 4; ++ks) {
            f16x8 b = *(const f16x8*)(bp + ks * 512);
            d = __builtin_amdgcn_mfma_f32_16x16x32_f16(a[ks], b, d, 0, 0, 0);
        }
#pragma unroll
        for (int reg = 0; reg < 4; ++reg) {
            int node = i0 + ((l >> 4) << 2) + reg;
            if (node < N) w1[(size_t)node * 128 + ct * 16 + (l & 15)] = f2bf(d[reg]);
        }
    }
#endif
}

// ---------------------------------------------------------------------------
// k_layer2: round-7 VERBATIM (passed).
// ---------------------------------------------------------------------------
__global__ __launch_bounds__(128) void k_layer2(const float* __restrict__ feat,
                                                const float* __restrict__ Wmlp,
                                                const u16* __restrict__ w1h,
                                                const float* __restrict__ alpha2,
                                                const float* __restrict__ lw,
                                                const float* __restrict__ prior,
                                                const int* __restrict__ adj,
                                                const int* __restrict__ nodes,
                                                float* __restrict__ out, int N) {
    __shared__ int s_idx[96];
    __shared__ float s_red[4];
    int b = blockIdx.x;
    int i = nodes[b];
    int t = threadIdx.x;

    if (t < 96) {
        int r = t >> 5, k = t & 31;
        s_idx[t] = adj[((size_t)r * N + i) * 32 + k];
    }
    __syncthreads();

    float mean[3];
#pragma unroll
    for (int r = 0; r < 3; ++r) {
        float acc = 0.f;
#pragma unroll
        for (int k = 0; k < 32; ++k)
            acc += bf16f(w1h[(size_t)s_idx[r * 32 + k] * 128 + t]);  // coalesced
        mean[r] = acc * (1.f / 32.f);
    }

    float et[3], eb[3], st = 0.f, sb = 0.f;
#pragma unroll
    for (int r = 0; r < 3; ++r) {
        et[r] = __expf(alpha2[t * 3 + r]);         st += et[r];
        eb[r] = __expf(alpha2[(128 + t) * 3 + r]); sb += eb[r];
    }
    float t2 = 0.f, wb = 0.f;
#pragma unroll
    for (int r = 0; r < 3; ++r) { t2 += et[r] * mean[r]; wb += eb[r] * mean[r]; }
    t2 /= st;
    wb /= sb;

    float t1 = bf16f(w1h[(size_t)i * 128 + t]);
    float t3 = t1 - wb;

    float p0 = t1 * lw[(64 + t) * 2 + 0] + t2 * lw[(192 + t) * 2 + 0] + t3 * lw[(320 + t) * 2 + 0];
    float p1 = t1 * lw[(64 + t) * 2 + 1] + t2 * lw[(192 + t) * 2 + 1] + t3 * lw[(320 + t) * 2 + 1];
    if (t < 64) {
        float t0 = 0.f;
#pragma unroll
        for (int k = 0; k < 25; ++k) t0 += feat[(size_t)i * 25 + k] * Wmlp[k * 64 + t];
        p0 += t0 * lw[t * 2 + 0];
        p1 += t0 * lw[t * 2 + 1];
    }

#pragma unroll
    for (int off = 32; off > 0; off >>= 1) {
        p0 += __shfl_down(p0, off, 64);
        p1 += __shfl_down(p1, off, 64);
    }
    int wv = t >> 6, lane = t & 63;
    if (lane == 0) { s_red[wv * 2 + 0] = p0; s_red[wv * 2 + 1] = p1; }
    __syncthreads();
    if (t == 0) {
        out[b * 2 + 0] = s_red[0] + s_red[2] + __logf(prior[0]);
        out[b * 2 + 1] = s_red[1] + s_red[3] + __logf(prior[1]);
    }
}

extern "C" void kernel_launch(void* const* d_in, const int* in_sizes, int n_in,
                              void* d_out, int out_size, void* d_ws, size_t ws_size,
                              hipStream_t stream) {
    const float* feat   = (const float*)d_in[0];  // [N,25]
    const float* Wmlp   = (const float*)d_in[1];  // [25,64]
    const float* alpha1 = (const float*)d_in[2];  // [128,3]
    const float* alpha2 = (const float*)d_in[3];  // [256,3]
    const float* lw     = (const float*)d_in[4];  // [448,2]
    const float* prior  = (const float*)d_in[5];  // [2]
    const int*   adj    = (const int*)d_in[6];    // [3,N,32]
    const int*   nodes  = (const int*)d_in[7];    // [B]
    float* out = (float*)d_out;

    int N = in_sizes[0] / 25;   // 50000
    int B = in_sizes[7];        // 1024

    // ws layout (25.7 MB total, < 28.8 MB proven-safe):
    //  region0: featp [N][32] bf16 (3.2MB) ALIASED with w1 [N][128] bf16 (12.8MB)
    //           (featp last read in k_gather; w1 first write in k_mfma - safe,
    //            and k_prep rewrites featp every call -> deterministic)
    //  region1: xbuf [N][128] f16 (12.8MB)
    //  region2: Bpack 16384 f16 (32KB)
    char* base = (char*)d_ws;
    u16* featp = (u16*)base;
    u16* w1    = (u16*)base;
    f16* xbuf  = (f16*)(base + (size_t)N * 128 * 2);
    f16* Bpack = (f16*)(base + (size_t)N * 128 * 2 + (size_t)N * 128 * 2);

    k_prep  <<<(N * 32 + 255) / 256, 256, 0, stream>>>(feat, featp, N);
    k_prepM <<<64,                   256, 0, stream>>>(Wmlp, alpha1, Bpack);
    k_gather<<<(N + 3) / 4,          256, 0, stream>>>(feat, featp, adj, xbuf, N);
    k_mfma  <<<((N + 15) / 16 + 3) / 4, 256, 0, stream>>>(xbuf, Bpack, w1, N);
    k_layer2<<<B,                    128, 0, stream>>>(feat, Wmlp, w1, alpha2, lw, prior, adj, nodes, out, N);
}

// Round 9
// 60.337 us; speedup vs baseline: 1.1008x; 1.1008x over previous
//
#include <hip/hip_runtime.h>

typedef unsigned int u32;
typedef unsigned short u16;
typedef _Float16 f16;
typedef __attribute__((ext_vector_type(2))) _Float16 f16x2;
typedef __attribute__((ext_vector_type(4))) _Float16 f16x4;
typedef __attribute__((ext_vector_type(8))) _Float16 f16x8;
typedef __attribute__((ext_vector_type(4))) float f32x4;

#if __has_builtin(__builtin_amdgcn_mfma_f32_16x16x16f16)
#define USE_K16 1
#else
#define USE_K16 0
#endif

__device__ __forceinline__ float bf16_lo(u32 u) { u32 x = u << 16; return __builtin_bit_cast(float, x); }
__device__ __forceinline__ float bf16_hi(u32 u) { u32 x = u & 0xffff0000u; return __builtin_bit_cast(float, x); }
__device__ __forceinline__ float bf16f(u16 v) { u32 x = ((u32)v) << 16; return __builtin_bit_cast(float, x); }
__device__ __forceinline__ u16 f2bf(float f) {  // round-to-nearest-even (proven)
    u32 x = __builtin_bit_cast(u32, f);
    return (u16)((x + 0x7fffu + ((x >> 16) & 1u)) >> 16);
}

// ---------------------------------------------------------------------------
// k_prep: featp[row][col] = bf16(feat[row][col]) for col<25, else 0. (VERBATIM r8)
// ---------------------------------------------------------------------------
__global__ __launch_bounds__(256) void k_prep(const float* __restrict__ feat,
                                              u16* __restrict__ featp, int N) {
    int t = blockIdx.x * 256 + threadIdx.x;
    int row = t >> 5, col = t & 31;
    if (row >= N) return;
    featp[(size_t)row * 32 + col] = (col < 25) ? f2bf(feat[(size_t)row * 25 + col]) : (u16)0;
}

// ---------------------------------------------------------------------------
// M[row][col]: folded layer-1 matrix (VERBATIM r8).
// ---------------------------------------------------------------------------
__device__ float m_val(int row, int col, const float* __restrict__ W,
                       const float* __restrict__ a1) {
    if (row >= 84) {
        int k = row - 84;
        return (k < 25 && col >= 64) ? W[k * 64 + (col - 64)] : 0.f;
    }
    int seg = (row >= 56) ? 2 : (row >= 28) ? 1 : 0;
    int k = row - seg * 28;
    if (k >= 25) return 0.f;
    int cc = (col < 64) ? col : col - 64;
    int arow = (col < 64) ? cc : 64 + cc;
    float e0 = __expf(a1[arow * 3 + 0]);
    float e1 = __expf(a1[arow * 3 + 1]);
    float e2 = __expf(a1[arow * 3 + 2]);
    float wt = ((seg == 0) ? e0 : (seg == 1) ? e1 : e2) / (e0 + e1 + e2);
    float v = W[k * 64 + cc] * wt * (1.f / 32.f);
    return (col < 64) ? v : -v;
}

// k_prepM: Bpack = M pre-packed into MFMA B-fragment order (VERBATIM r8).
__global__ __launch_bounds__(256) void k_prepM(const float* __restrict__ W,
                                               const float* __restrict__ a1,
                                               f16* __restrict__ Bpack) {
    int idx = blockIdx.x * 256 + threadIdx.x;   // 64 blocks -> 16384
#if USE_K16
    int j = idx & 3, l = (idx >> 2) & 63, ks = (idx >> 8) & 7, ct = idx >> 11;
    int row = ks * 16 + ((l >> 4) << 2) + j;
#else
    int j = idx & 7, l = (idx >> 3) & 63, ks = (idx >> 9) & 3, ct = idx >> 11;
    int row = ks * 32 + ((l >> 4) << 3) + j;
#endif
    int col = ct * 16 + (l & 15);
    float v = (row < 112) ? m_val(row, col, W, a1) : 0.f;
    Bpack[idx] = (f16)v;
}

// ---------------------------------------------------------------------------
// k_layer1f: FUSED gather + MFMA. One block (4 waves) per 16 nodes.
// Gather: wave w, group g=lane>>4 owns node i0+w*4+g; c=lane&15 = row dword.
//   Indices preloaded once per relation (lane c holds neighbor c / 16+c),
//   broadcast via UNIFORM-k width-16 shfl (round-2-proven shfl mode).
//   Group reads its node's neighbor-k 64B featp row; lane (g,c) accumulates
//   bf16 cols 2c,2c+1 in f32 -> NO cross-lane reduction needed.
// x-tile in LDS [16][136] f16 (cols: 3x28 neighbor sums | 84+25 self feat |
//   zeros to 127; stride 136 keeps 16B alignment + spreads banks).
// MFMA: round-8-proven math, A-frags from LDS, wave w does ct = 2w, 2w+1.
// ---------------------------------------------------------------------------
__global__ __launch_bounds__(256) void k_layer1f(const float* __restrict__ feat,
                                                 const u16* __restrict__ featp,
                                                 const int* __restrict__ adj,
                                                 const f16* __restrict__ Bpack,
                                                 u16* __restrict__ w1, int N) {
    __shared__ f16 x[16][136];
    int w = threadIdx.x >> 6;
    int l = threadIdx.x & 63;
    int g = l >> 4;
    int c = l & 15;
    int i0 = blockIdx.x * 16;
    int node = i0 + w * 4 + g;
    int nsafe = (node < N) ? node : 0;

    const u32* fp = (const u32*)featp;
#pragma unroll
    for (int r = 0; r < 3; ++r) {
        const int* arow = adj + ((size_t)r * N + nsafe) * 32;
        int idxA = __builtin_nontemporal_load(arow + c);        // neighbors 0..15
        int idxB = __builtin_nontemporal_load(arow + 16 + c);   // neighbors 16..31
        float s0 = 0.f, s1 = 0.f;
#pragma unroll
        for (int k = 0; k < 16; ++k) {
            int nb = __shfl(idxA, k, 16);       // uniform k: group g gets ITS neighbor k
            u32 u = fp[(size_t)nb * 16 + c];    // 16 lanes read one 64B row, coalesced
            s0 += bf16_lo(u);
            s1 += bf16_hi(u);
        }
#pragma unroll
        for (int k = 0; k < 16; ++k) {
            int nb = __shfl(idxB, k, 16);
            u32 u = fp[(size_t)nb * 16 + c];
            s0 += bf16_lo(u);
            s1 += bf16_hi(u);
        }
        if (c < 14) {   // cols r*28 + {2c,2c+1}; featp pad keeps c>=12.5 sums zero
            f16x2 o;
            o[0] = (f16)s0;
            o[1] = (f16)s1;
            *(u32*)&x[w * 4 + g][r * 28 + 2 * c] = __builtin_bit_cast(u32, o);
        }
    }
    // self-feat segment cols 84..108, zeros 109..127 (cols 128..135 never read)
    for (int e = threadIdx.x; e < 16 * 44; e += 256) {
        int row = e / 44, col = 84 + e % 44;
        int nrow = i0 + row;
        float v = (col < 109 && nrow < N) ? feat[(size_t)nrow * 25 + (col - 84)] : 0.f;
        x[row][col] = (f16)v;
    }
    __syncthreads();

    // ---- MFMA phase (round-8-proven; A from LDS; 2 ct-tiles per wave) ----
#if USE_K16
    f16x4 a[8];
    const f16* xrow = &x[l & 15][(l >> 4) << 2];
#pragma unroll
    for (int ks = 0; ks < 8; ++ks) a[ks] = *(const f16x4*)(xrow + ks * 16);
#pragma unroll
    for (int ctt = 0; ctt < 2; ++ctt) {
        int ct = w * 2 + ctt;
        f32x4 d = {0.f, 0.f, 0.f, 0.f};
        const f16* bp = Bpack + ((size_t)(ct * 8) * 64 + l) * 4;
#pragma unroll
        for (int ks = 0; ks < 8; ++ks) {
            f16x4 b = *(const f16x4*)(bp + ks * 256);
            d = __builtin_amdgcn_mfma_f32_16x16x16f16(a[ks], b, d, 0, 0, 0);
        }
#pragma unroll
        for (int reg = 0; reg < 4; ++reg) {
            int n2 = i0 + ((l >> 4) << 2) + reg;
            if (n2 < N) w1[(size_t)n2 * 128 + ct * 16 + (l & 15)] = f2bf(d[reg]);
        }
    }
#else
    f16x8 a[4];
    const f16* xrow = &x[l & 15][(l >> 4) << 3];
#pragma unroll
    for (int ks = 0; ks < 4; ++ks) a[ks] = *(const f16x8*)(xrow + ks * 32);
#pragma unroll
    for (int ctt = 0; ctt < 2; ++ctt) {
        int ct = w * 2 + ctt;
        f32x4 d = {0.f, 0.f, 0.f, 0.f};
        const f16* bp = Bpack + ((size_t)(ct * 4) * 64 + l) * 8;
#pragma unroll
        for (int ks = 0; ks < 4; ++ks) {
            f16x8 b = *(const f16x8*)(bp + ks * 512);
            d = __builtin_amdgcn_mfma_f32_16x16x32_f16(a[ks], b, d, 0, 0, 0);
        }
#pragma unroll
        for (int reg = 0; reg < 4; ++reg) {
            int n2 = i0 + ((l >> 4) << 2) + reg;
            if (n2 < N) w1[(size_t)n2 * 128 + ct * 16 + (l & 15)] = f2bf(d[reg]);
        }
    }
#endif
}

// ---------------------------------------------------------------------------
// k_layer2: round-8 VERBATIM (passed).
// ---------------------------------------------------------------------------
__global__ __launch_bounds__(128) void k_layer2(const float* __restrict__ feat,
                                                const float* __restrict__ Wmlp,
                                                const u16* __restrict__ w1h,
                                                const float* __restrict__ alpha2,
                                                const float* __restrict__ lw,
                                                const float* __restrict__ prior,
                                                const int* __restrict__ adj,
                                                const int* __restrict__ nodes,
                                                float* __restrict__ out, int N) {
    __shared__ int s_idx[96];
    __shared__ float s_red[4];
    int b = blockIdx.x;
    int i = nodes[b];
    int t = threadIdx.x;

    if (t < 96) {
        int r = t >> 5, k = t & 31;
        s_idx[t] = adj[((size_t)r * N + i) * 32 + k];
    }
    __syncthreads();

    float mean[3];
#pragma unroll
    for (int r = 0; r < 3; ++r) {
        float acc = 0.f;
#pragma unroll
        for (int k = 0; k < 32; ++k)
            acc += bf16f(w1h[(size_t)s_idx[r * 32 + k] * 128 + t]);  // coalesced
        mean[r] = acc * (1.f / 32.f);
    }

    float et[3], eb[3], st = 0.f, sb = 0.f;
#pragma unroll
    for (int r = 0; r < 3; ++r) {
        et[r] = __expf(alpha2[t * 3 + r]);         st += et[r];
        eb[r] = __expf(alpha2[(128 + t) * 3 + r]); sb += eb[r];
    }
    float t2 = 0.f, wb = 0.f;
#pragma unroll
    for (int r = 0; r < 3; ++r) { t2 += et[r] * mean[r]; wb += eb[r] * mean[r]; }
    t2 /= st;
    wb /= sb;

    float t1 = bf16f(w1h[(size_t)i * 128 + t]);
    float t3 = t1 - wb;

    float p0 = t1 * lw[(64 + t) * 2 + 0] + t2 * lw[(192 + t) * 2 + 0] + t3 * lw[(320 + t) * 2 + 0];
    float p1 = t1 * lw[(64 + t) * 2 + 1] + t2 * lw[(192 + t) * 2 + 1] + t3 * lw[(320 + t) * 2 + 1];
    if (t < 64) {
        float t0 = 0.f;
#pragma unroll
        for (int k = 0; k < 25; ++k) t0 += feat[(size_t)i * 25 + k] * Wmlp[k * 64 + t];
        p0 += t0 * lw[t * 2 + 0];
        p1 += t0 * lw[t * 2 + 1];
    }

#pragma unroll
    for (int off = 32; off > 0; off >>= 1) {
        p0 += __shfl_down(p0, off, 64);
        p1 += __shfl_down(p1, off, 64);
    }
    int wv = t >> 6, lane = t & 63;
    if (lane == 0) { s_red[wv * 2 + 0] = p0; s_red[wv * 2 + 1] = p1; }
    __syncthreads();
    if (t == 0) {
        out[b * 2 + 0] = s_red[0] + s_red[2] + __logf(prior[0]);
        out[b * 2 + 1] = s_red[1] + s_red[3] + __logf(prior[1]);
    }
}

extern "C" void kernel_launch(void* const* d_in, const int* in_sizes, int n_in,
                              void* d_out, int out_size, void* d_ws, size_t ws_size,
                              hipStream_t stream) {
    const float* feat   = (const float*)d_in[0];  // [N,25]
    const float* Wmlp   = (const float*)d_in[1];  // [25,64]
    const float* alpha1 = (const float*)d_in[2];  // [128,3]
    const float* alpha2 = (const float*)d_in[3];  // [256,3]
    const float* lw     = (const float*)d_in[4];  // [448,2]
    const float* prior  = (const float*)d_in[5];  // [2]
    const int*   adj    = (const int*)d_in[6];    // [3,N,32]
    const int*   nodes  = (const int*)d_in[7];    // [B]
    float* out = (float*)d_out;

    int N = in_sizes[0] / 25;   // 50000
    int B = in_sizes[7];        // 1024

    // ws: featp [N][32] u16 (3.2MB) | w1 [N][128] u16 (12.8MB) | Bpack 32KB
    // total ~16.03MB (< 28.8MB proven-safe). NO aliasing.
    char* base = (char*)d_ws;
    u16* featp = (u16*)base;
    u16* w1    = (u16*)(base + (size_t)N * 32 * 2);
    f16* Bpack = (f16*)(base + (size_t)N * 32 * 2 + (size_t)N * 128 * 2);

    k_prep   <<<(N * 32 + 255) / 256, 256, 0, stream>>>(feat, featp, N);
    k_prepM  <<<64,                   256, 0, stream>>>(Wmlp, alpha1, Bpack);
    k_layer1f<<<(N + 15) / 16,        256, 0, stream>>>(feat, featp, adj, Bpack, w1, N);
    k_layer2 <<<B,                    128, 0, stream>>>(feat, Wmlp, w1, alpha2, lw, prior, adj, nodes, out, N);
}

// Round 10
// 55.164 us; speedup vs baseline: 1.2040x; 1.0938x over previous
//
#include <hip/hip_runtime.h>

typedef unsigned int u32;
typedef unsigned short u16;
typedef _Float16 f16;
typedef __attribute__((ext_vector_type(2))) _Float16 f16x2;
typedef __attribute__((ext_vector_type(4))) _Float16 f16x4;
typedef __attribute__((ext_vector_type(8))) _Float16 f16x8;
typedef __attribute__((ext_vector_type(4))) float f32x4;
typedef __attribute__((ext_vector_type(4))) u32 u32x4;

#if __has_builtin(__builtin_amdgcn_mfma_f32_16x16x16f16)
#define USE_K16 1
#else
#define USE_K16 0
#endif

__device__ __forceinline__ float bf16_lo(u32 u) { u32 x = u << 16; return __builtin_bit_cast(float, x); }
__device__ __forceinline__ float bf16_hi(u32 u) { u32 x = u & 0xffff0000u; return __builtin_bit_cast(float, x); }
__device__ __forceinline__ float bf16f(u16 v) { u32 x = ((u32)v) << 16; return __builtin_bit_cast(float, x); }
__device__ __forceinline__ u16 f2bf(float f) {  // round-to-nearest-even (proven)
    u32 x = __builtin_bit_cast(u32, f);
    return (u16)((x + 0x7fffu + ((x >> 16) & 1u)) >> 16);
}

// ---------------------------------------------------------------------------
// k_prep: featp[row][col] = bf16(feat[row][col]) for col<25, else 0. (VERBATIM r9)
// ---------------------------------------------------------------------------
__global__ __launch_bounds__(256) void k_prep(const float* __restrict__ feat,
                                              u16* __restrict__ featp, int N) {
    int t = blockIdx.x * 256 + threadIdx.x;
    int row = t >> 5, col = t & 31;
    if (row >= N) return;
    featp[(size_t)row * 32 + col] = (col < 25) ? f2bf(feat[(size_t)row * 25 + col]) : (u16)0;
}

// ---------------------------------------------------------------------------
// M[row][col]: folded layer-1 matrix, K=128 row map:
//  rows seg*32+k (seg<3, k<25): col<64:  W[k][col]*softmaxT(col)[seg]/32
//                               col>=64: -W[k][col-64]*softmaxB(col-64)[seg]/32
//  rows 96+k (k<25):            col>=64: W[k][col-64] (self), else 0
//  all other rows: 0
// ---------------------------------------------------------------------------
__device__ float m_val(int row, int col, const float* __restrict__ W,
                       const float* __restrict__ a1) {
    if (row >= 96) {
        int k = row - 96;
        return (k < 25 && col >= 64) ? W[k * 64 + (col - 64)] : 0.f;
    }
    int seg = row >> 5;
    int k = row & 31;
    if (k >= 25) return 0.f;
    int cc = (col < 64) ? col : col - 64;
    int arow = (col < 64) ? cc : 64 + cc;
    float e0 = __expf(a1[arow * 3 + 0]);
    float e1 = __expf(a1[arow * 3 + 1]);
    float e2 = __expf(a1[arow * 3 + 2]);
    float wt = ((seg == 0) ? e0 : (seg == 1) ? e1 : e2) / (e0 + e1 + e2);
    float v = W[k * 64 + cc] * wt * (1.f / 32.f);
    return (col < 64) ? v : -v;
}

// k_prepM: Bpack = M pre-packed into MFMA B-fragment order (r8/r9-proven packing).
__global__ __launch_bounds__(256) void k_prepM(const float* __restrict__ W,
                                               const float* __restrict__ a1,
                                               f16* __restrict__ Bpack) {
    int idx = blockIdx.x * 256 + threadIdx.x;   // 64 blocks -> 16384
#if USE_K16
    int j = idx & 3, l = (idx >> 2) & 63, ks = (idx >> 8) & 7, ct = idx >> 11;
    int row = ks * 16 + ((l >> 4) << 2) + j;
#else
    int j = idx & 7, l = (idx >> 3) & 63, ks = (idx >> 9) & 3, ct = idx >> 11;
    int row = ks * 32 + ((l >> 4) << 3) + j;
#endif
    int col = ct * 16 + (l & 15);
    Bpack[idx] = (f16)m_val(row, col, W, a1);
}

// ---------------------------------------------------------------------------
// k_layer1f v2: FUSED gather + MFMA. One block (4 waves) per 16 nodes.
//  Stage: 16x96 adj indices into LDS (k_layer2-proven pattern; stride 104
//         de-banks the per-lane ds_reads), self-feat into x cols 96..120.
//  Gather: wave w owns nodes w*4..w*4+3. Lane roles: q=l>>4 neighbor
//         sub-offset, m=(l>>2)&3 node, e=l&3 16B row segment. Step k loads
//         neighbor (k+q) of node m, segment e: one instruction = 16 distinct
//         64B rows = 1KB; only 8 chained loads per relation (was 32).
//         Reduce over q with PROVEN shfl_xor masks 16/32; lanes q==0 write
//         8 f16 col-sums to x[node][r*32 + e*8].
//  MFMA: r9-verbatim math; x cols: 3x32 sums | 96..120 self | zeros to 127.
// ---------------------------------------------------------------------------
__global__ __launch_bounds__(256) void k_layer1f(const float* __restrict__ feat,
                                                 const u16* __restrict__ featp,
                                                 const int* __restrict__ adj,
                                                 const f16* __restrict__ Bpack,
                                                 u16* __restrict__ w1, int N) {
    __shared__ f16 x[16][136];
    __shared__ int s_idx[16][104];   // 96 used; stride 104 spreads banks
    int tid = threadIdx.x;
    int i0 = blockIdx.x * 16;

    {   // stage indices: thread t -> node t>>4, lane16 t&15; 6 coalesced loads
        int node = tid >> 4, l16 = tid & 15;
        int nsafe = (i0 + node < N) ? (i0 + node) : 0;
#pragma unroll
        for (int j = 0; j < 6; ++j) {
            int jj = l16 + j * 16;        // 0..95
            int rr = jj >> 5, kk = jj & 31;
            s_idx[node][jj] = __builtin_nontemporal_load(adj + ((size_t)rr * N + nsafe) * 32 + kk);
        }
    }
    // stage self-feat cols 96..120, zeros 121..135
    for (int e2 = tid; e2 < 16 * 40; e2 += 256) {
        int row = e2 / 40, col = 96 + e2 % 40;
        int nrow = i0 + row;
        float v = (col < 121 && nrow < N) ? feat[(size_t)nrow * 25 + (col - 96)] : 0.f;
        x[row][col] = (f16)v;
    }
    __syncthreads();

    int w = tid >> 6;
    int l = tid & 63;
    int q = l >> 4;        // neighbor sub-offset 0..3
    int m = (l >> 2) & 3;  // node within wave
    int e = l & 3;         // 16B segment of the 64B row
    int nodeLocal = w * 4 + m;
    const u32* fp = (const u32*)featp;   // 16 u32 per 64B row

#pragma unroll
    for (int r = 0; r < 3; ++r) {
        float acc[8];
#pragma unroll
        for (int j = 0; j < 8; ++j) acc[j] = 0.f;
#pragma unroll
        for (int k = 0; k < 32; k += 4) {
            int nb = s_idx[nodeLocal][r * 32 + k + q];          // per-lane ds_read
            u32x4 v = *(const u32x4*)(fp + (size_t)nb * 16 + e * 4);  // 16B of row
            acc[0] += bf16_lo(v[0]); acc[1] += bf16_hi(v[0]);
            acc[2] += bf16_lo(v[1]); acc[3] += bf16_hi(v[1]);
            acc[4] += bf16_lo(v[2]); acc[5] += bf16_hi(v[2]);
            acc[6] += bf16_lo(v[3]); acc[7] += bf16_hi(v[3]);
        }
#pragma unroll
        for (int j = 0; j < 8; ++j) {   // reduce over q: PROVEN masks 16,32 only
            acc[j] += __shfl_xor(acc[j], 16, 64);
            acc[j] += __shfl_xor(acc[j], 32, 64);
        }
        if (q == 0) {   // 16 lanes write 16B each: cols r*32 + e*8 .. +7
            f16x2 p0, p1, p2, p3;
            p0[0] = (f16)acc[0]; p0[1] = (f16)acc[1];
            p1[0] = (f16)acc[2]; p1[1] = (f16)acc[3];
            p2[0] = (f16)acc[4]; p2[1] = (f16)acc[5];
            p3[0] = (f16)acc[6]; p3[1] = (f16)acc[7];
            u32x4 ov;
            ov[0] = __builtin_bit_cast(u32, p0);
            ov[1] = __builtin_bit_cast(u32, p1);
            ov[2] = __builtin_bit_cast(u32, p2);
            ov[3] = __builtin_bit_cast(u32, p3);
            *(u32x4*)&x[nodeLocal][r * 32 + e * 8] = ov;
        }
    }
    __syncthreads();

    // ---- MFMA phase (r9 VERBATIM; A from LDS; 2 ct-tiles per wave) ----
#if USE_K16
    f16x4 a[8];
    const f16* xrow = &x[l & 15][(l >> 4) << 2];
#pragma unroll
    for (int ks = 0; ks < 8; ++ks) a[ks] = *(const f16x4*)(xrow + ks * 16);
#pragma unroll
    for (int ctt = 0; ctt < 2; ++ctt) {
        int ct = w * 2 + ctt;
        f32x4 d = {0.f, 0.f, 0.f, 0.f};
        const f16* bp = Bpack + ((size_t)(ct * 8) * 64 + l) * 4;
#pragma unroll
        for (int ks = 0; ks < 8; ++ks) {
            f16x4 b = *(const f16x4*)(bp + ks * 256);
            d = __builtin_amdgcn_mfma_f32_16x16x16f16(a[ks], b, d, 0, 0, 0);
        }
#pragma unroll
        for (int reg = 0; reg < 4; ++reg) {
            int n2 = i0 + ((l >> 4) << 2) + reg;
            if (n2 < N) w1[(size_t)n2 * 128 + ct * 16 + (l & 15)] = f2bf(d[reg]);
        }
    }
#else
    f16x8 a[4];
    const f16* xrow = &x[l & 15][(l >> 4) << 3];
#pragma unroll
    for (int ks = 0; ks < 4; ++ks) a[ks] = *(const f16x8*)(xrow + ks * 32);
#pragma unroll
    for (int ctt = 0; ctt < 2; ++ctt) {
        int ct = w * 2 + ctt;
        f32x4 d = {0.f, 0.f, 0.f, 0.f};
        const f16* bp = Bpack + ((size_t)(ct * 4) * 64 + l) * 8;
#pragma unroll
        for (int ks = 0; ks < 4; ++ks) {
            f16x8 b = *(const f16x8*)(bp + ks * 512);
            d = __builtin_amdgcn_mfma_f32_16x16x32_f16(a[ks], b, d, 0, 0, 0);
        }
#pragma unroll
        for (int reg = 0; reg < 4; ++reg) {
            int n2 = i0 + ((l >> 4) << 2) + reg;
            if (n2 < N) w1[(size_t)n2 * 128 + ct * 16 + (l & 15)] = f2bf(d[reg]);
        }
    }
#endif
}

// ---------------------------------------------------------------------------
// k_layer2: round-9 VERBATIM (passed).
// ---------------------------------------------------------------------------
__global__ __launch_bounds__(128) void k_layer2(const float* __restrict__ feat,
                                                const float* __restrict__ Wmlp,
                                                const u16* __restrict__ w1h,
                                                const float* __restrict__ alpha2,
                                                const float* __restrict__ lw,
                                                const float* __restrict__ prior,
                                                const int* __restrict__ adj,
                                                const int* __restrict__ nodes,
                                                float* __restrict__ out, int N) {
    __shared__ int s_idx[96];
    __shared__ float s_red[4];
    int b = blockIdx.x;
    int i = nodes[b];
    int t = threadIdx.x;

    if (t < 96) {
        int r = t >> 5, k = t & 31;
        s_idx[t] = adj[((size_t)r * N + i) * 32 + k];
    }
    __syncthreads();

    float mean[3];
#pragma unroll
    for (int r = 0; r < 3; ++r) {
        float acc = 0.f;
#pragma unroll
        for (int k = 0; k < 32; ++k)
            acc += bf16f(w1h[(size_t)s_idx[r * 32 + k] * 128 + t]);  // coalesced
        mean[r] = acc * (1.f / 32.f);
    }

    float et[3], eb[3], st = 0.f, sb = 0.f;
#pragma unroll
    for (int r = 0; r < 3; ++r) {
        et[r] = __expf(alpha2[t * 3 + r]);         st += et[r];
        eb[r] = __expf(alpha2[(128 + t) * 3 + r]); sb += eb[r];
    }
    float t2 = 0.f, wb = 0.f;
#pragma unroll
    for (int r = 0; r < 3; ++r) { t2 += et[r] * mean[r]; wb += eb[r] * mean[r]; }
    t2 /= st;
    wb /= sb;

    float t1 = bf16f(w1h[(size_t)i * 128 + t]);
    float t3 = t1 - wb;

    float p0 = t1 * lw[(64 + t) * 2 + 0] + t2 * lw[(192 + t) * 2 + 0] + t3 * lw[(320 + t) * 2 + 0];
    float p1 = t1 * lw[(64 + t) * 2 + 1] + t2 * lw[(192 + t) * 2 + 1] + t3 * lw[(320 + t) * 2 + 1];
    if (t < 64) {
        float t0 = 0.f;
#pragma unroll
        for (int k = 0; k < 25; ++k) t0 += feat[(size_t)i * 25 + k] * Wmlp[k * 64 + t];
        p0 += t0 * lw[t * 2 + 0];
        p1 += t0 * lw[t * 2 + 1];
    }

#pragma unroll
    for (int off = 32; off > 0; off >>= 1) {
        p0 += __shfl_down(p0, off, 64);
        p1 += __shfl_down(p1, off, 64);
    }
    int wv = t >> 6, lane = t & 63;
    if (lane == 0) { s_red[wv * 2 + 0] = p0; s_red[wv * 2 + 1] = p1; }
    __syncthreads();
    if (t == 0) {
        out[b * 2 + 0] = s_red[0] + s_red[2] + __logf(prior[0]);
        out[b * 2 + 1] = s_red[1] + s_red[3] + __logf(prior[1]);
    }
}

extern "C" void kernel_launch(void* const* d_in, const int* in_sizes, int n_in,
                              void* d_out, int out_size, void* d_ws, size_t ws_size,
                              hipStream_t stream) {
    const float* feat   = (const float*)d_in[0];  // [N,25]
    const float* Wmlp   = (const float*)d_in[1];  // [25,64]
    const float* alpha1 = (const float*)d_in[2];  // [128,3]
    const float* alpha2 = (const float*)d_in[3];  // [256,3]
    const float* lw     = (const float*)d_in[4];  // [448,2]
    const float* prior  = (const float*)d_in[5];  // [2]
    const int*   adj    = (const int*)d_in[6];    // [3,N,32]
    const int*   nodes  = (const int*)d_in[7];    // [B]
    float* out = (float*)d_out;

    int N = in_sizes[0] / 25;   // 50000
    int B = in_sizes[7];        // 1024

    // ws: featp [N][32] u16 (3.2MB) | w1 [N][128] u16 (12.8MB) | Bpack 32KB
    // total ~16.03MB (< 28.8MB proven-safe). NO aliasing.
    char* base = (char*)d_ws;
    u16* featp = (u16*)base;
    u16* w1    = (u16*)(base + (size_t)N * 32 * 2);
    f16* Bpack = (f16*)(base + (size_t)N * 32 * 2 + (size_t)N * 128 * 2);

    k_prep   <<<(N * 32 + 255) / 256, 256, 0, stream>>>(feat, featp, N);
    k_prepM  <<<64,                   256, 0, stream>>>(Wmlp, alpha1, Bpack);
    k_layer1f<<<(N + 15) / 16,        256, 0, stream>>>(feat, featp, adj, Bpack, w1, N);
    k_layer2 <<<B,                    128, 0, stream>>>(feat, Wmlp, w1, alpha2, lw, prior, adj, nodes, out, N);
}